// Round 1
// baseline (270.497 us; speedup 1.0000x reference)
//
#include <hip/hip_runtime.h>

constexpr int FD = 256;   // feature dim (D == H == 256)

// ---------------- graph preprocessing ----------------

__global__ __launch_bounds__(256) void k_init(int* counts, int* fill, int n) {
    int i = blockIdx.x * 256 + threadIdx.x;
    if (i < n) { counts[i] = 0; fill[i] = 0; }
}

__global__ __launch_bounds__(256) void k_count(const int* __restrict__ dst,
                                               int* __restrict__ counts, int E) {
    int i = blockIdx.x * 256 + threadIdx.x;
    if (i < E) atomicAdd(&counts[dst[i]], 1);
}

__global__ __launch_bounds__(256) void k_dinv(const int* __restrict__ counts,
                                              float* __restrict__ dinv, int n) {
    int i = blockIdx.x * 256 + threadIdx.x;
    if (i < n) dinv[i] = rsqrtf((float)(counts[i] + 1));  // +1 = self-loop
}

__global__ __launch_bounds__(256) void k_scan(const int* __restrict__ counts,
                                              int* __restrict__ rowptr, int n) {
    __shared__ int part[256];
    int t = threadIdx.x;
    int chunk = (n + 255) >> 8;
    int b = t * chunk;
    int e = min(b + chunk, n);
    int sum = 0;
    for (int i = b; i < e; i++) sum += counts[i];
    part[t] = sum;
    __syncthreads();
    for (int o = 1; o < 256; o <<= 1) {
        int v = (t >= o) ? part[t - o] : 0;
        __syncthreads();
        part[t] += v;
        __syncthreads();
    }
    int run = (t == 0) ? 0 : part[t - 1];
    for (int i = b; i < e; i++) { rowptr[i] = run; run += counts[i]; }
    if (t == 255) rowptr[n] = run;
}

__global__ __launch_bounds__(256) void k_scatter(const int* __restrict__ src,
                                                 const int* __restrict__ dst,
                                                 const int* __restrict__ rowptr,
                                                 int* __restrict__ fill,
                                                 const float* __restrict__ dinv,
                                                 int* __restrict__ col,
                                                 float* __restrict__ val, int E) {
    int i = blockIdx.x * 256 + threadIdx.x;
    if (i < E) {
        int d = dst[i], s = src[i];
        int pos = rowptr[d] + atomicAdd(&fill[d], 1);
        col[pos] = s;
        val[pos] = dinv[s];
    }
}

// ---------------- dense GEMM: C[m,j] = sum_k A[m,k] * W[j,k] ----------------
// 64x64 tile, 256 threads, 4x4 accum per thread, K staged K-major in LDS.

__global__ __launch_bounds__(256) void k_gemm(const float* __restrict__ A,
                                              const float* __restrict__ W,
                                              float* __restrict__ C, int M) {
    __shared__ float As[16][68];
    __shared__ float Bs[16][68];
    int tid = threadIdx.x;
    int tx = tid & 15, ty = tid >> 4;
    int m0 = blockIdx.x * 64, c0 = blockIdx.y * 64;
    int lrow = tid >> 2;          // 0..63
    int lk4  = (tid & 3) * 4;     // 0,4,8,12
    float acc[4][4] = {};
    for (int k0 = 0; k0 < FD; k0 += 16) {
        int gr = m0 + lrow;
        float4 av = (gr < M) ? *(const float4*)(A + (size_t)gr * FD + k0 + lk4)
                             : make_float4(0.f, 0.f, 0.f, 0.f);
        float4 wv = *(const float4*)(W + (size_t)(c0 + lrow) * FD + k0 + lk4);
        __syncthreads();   // previous compute done reading LDS
        As[lk4 + 0][lrow] = av.x; As[lk4 + 1][lrow] = av.y;
        As[lk4 + 2][lrow] = av.z; As[lk4 + 3][lrow] = av.w;
        Bs[lk4 + 0][lrow] = wv.x; Bs[lk4 + 1][lrow] = wv.y;
        Bs[lk4 + 2][lrow] = wv.z; Bs[lk4 + 3][lrow] = wv.w;
        __syncthreads();
        #pragma unroll
        for (int kk = 0; kk < 16; kk++) {
            float4 a = *(const float4*)&As[kk][ty * 4];
            float4 b = *(const float4*)&Bs[kk][tx * 4];
            float a4[4] = {a.x, a.y, a.z, a.w};
            float b4[4] = {b.x, b.y, b.z, b.w};
            #pragma unroll
            for (int i = 0; i < 4; i++)
                #pragma unroll
                for (int j = 0; j < 4; j++)
                    acc[i][j] = fmaf(a4[i], b4[j], acc[i][j]);
        }
    }
    #pragma unroll
    for (int i = 0; i < 4; i++) {
        int gr = m0 + ty * 4 + i;
        if (gr < M) {
            float4 o = make_float4(acc[i][0], acc[i][1], acc[i][2], acc[i][3]);
            *(float4*)(C + (size_t)gr * FD + c0 + tx * 4) = o;
        }
    }
}

// ---------------- SpMM: out[n,:] = relu(dinv[n]*(sum val*H[col] + dinv[n]*H[n]) + b) ----

__global__ __launch_bounds__(256) void k_spmm(const float* __restrict__ H,
                                              const int* __restrict__ rowptr,
                                              const int* __restrict__ col,
                                              const float* __restrict__ val,
                                              const float* __restrict__ dinv,
                                              const float* __restrict__ bias,
                                              float* __restrict__ out, int N) {
    int row = blockIdx.x * 4 + (threadIdx.x >> 6);
    if (row >= N) return;
    int lane = threadIdx.x & 63;
    int s = rowptr[row], e = rowptr[row + 1];
    float4 acc = make_float4(0.f, 0.f, 0.f, 0.f);
    int i = s;
    for (; i + 1 < e; i += 2) {
        int   c0 = col[i],   c1 = col[i + 1];
        float v0 = val[i],   v1 = val[i + 1];
        float4 h0 = ((const float4*)(H + (size_t)c0 * FD))[lane];
        float4 h1 = ((const float4*)(H + (size_t)c1 * FD))[lane];
        acc.x += v0 * h0.x + v1 * h1.x;
        acc.y += v0 * h0.y + v1 * h1.y;
        acc.z += v0 * h0.z + v1 * h1.z;
        acc.w += v0 * h0.w + v1 * h1.w;
    }
    if (i < e) {
        int c = col[i];
        float v = val[i];
        float4 h = ((const float4*)(H + (size_t)c * FD))[lane];
        acc.x += v * h.x; acc.y += v * h.y; acc.z += v * h.z; acc.w += v * h.w;
    }
    float di = dinv[row];
    float4 hs = ((const float4*)(H + (size_t)row * FD))[lane];
    acc.x += di * hs.x; acc.y += di * hs.y; acc.z += di * hs.z; acc.w += di * hs.w;
    float4 bb = ((const float4*)bias)[lane];
    float4 o;
    o.x = fmaxf(fmaf(di, acc.x, bb.x), 0.f);
    o.y = fmaxf(fmaf(di, acc.y, bb.y), 0.f);
    o.z = fmaxf(fmaf(di, acc.z, bb.z), 0.f);
    o.w = fmaxf(fmaf(di, acc.w, bb.w), 0.f);
    ((float4*)(out + (size_t)row * FD))[lane] = o;
}

// ---------------- launch ----------------

extern "C" void kernel_launch(void* const* d_in, const int* in_sizes, int n_in,
                              void* d_out, int out_size, void* d_ws, size_t ws_size,
                              hipStream_t stream) {
    const float* x  = (const float*)d_in[0];
    const int*   ei = (const int*)d_in[1];
    const float* W1 = (const float*)d_in[2];
    const float* b1 = (const float*)d_in[3];
    const float* W2 = (const float*)d_in[4];
    const float* b2 = (const float*)d_in[5];
    const float* W3 = (const float*)d_in[6];
    const float* b3 = (const float*)d_in[7];
    float* out = (float*)d_out;

    int N = in_sizes[0] / FD;
    int E = in_sizes[1] / 2;
    const int* src = ei;
    const int* dst = ei + E;

    char* base = (char*)d_ws;
    size_t off = 0;
    auto alloc = [&](size_t bytes) {
        char* p = base + off;
        off = (off + bytes + 255) & ~(size_t)255;
        return p;
    };
    int*   counts = (int*)  alloc((size_t)N * 4);
    int*   fill   = (int*)  alloc((size_t)N * 4);
    int*   rowptr = (int*)  alloc((size_t)(N + 1) * 4);
    float* dinv   = (float*)alloc((size_t)N * 4);
    int*   col    = (int*)  alloc((size_t)E * 4);
    float* val    = (float*)alloc((size_t)E * 4);
    float* Htmp   = (float*)alloc((size_t)N * FD * 4);
    float* bufA   = (float*)alloc((size_t)N * FD * 4);

    int gN = (N + 255) / 256, gE = (E + 255) / 256;
    k_init   <<<gN, 256, 0, stream>>>(counts, fill, N);
    k_count  <<<gE, 256, 0, stream>>>(dst, counts, E);
    k_dinv   <<<gN, 256, 0, stream>>>(counts, dinv, N);
    k_scan   <<<1, 256, 0, stream>>>(counts, rowptr, N);
    k_scatter<<<gE, 256, 0, stream>>>(src, dst, rowptr, fill, dinv, col, val, E);

    dim3 gg((N + 63) / 64, FD / 64);
    int gs = (N + 3) / 4;
    // layer 1
    k_gemm<<<gg, 256, 0, stream>>>(x, W1, Htmp, N);
    k_spmm<<<gs, 256, 0, stream>>>(Htmp, rowptr, col, val, dinv, b1, bufA, N);
    // layer 2
    k_gemm<<<gg, 256, 0, stream>>>(bufA, W2, Htmp, N);
    k_spmm<<<gs, 256, 0, stream>>>(Htmp, rowptr, col, val, dinv, b2, bufA, N);
    // layer 3
    k_gemm<<<gg, 256, 0, stream>>>(bufA, W3, Htmp, N);
    k_spmm<<<gs, 256, 0, stream>>>(Htmp, rowptr, col, val, dinv, b3, out, N);
}

// Round 2
// 236.622 us; speedup vs baseline: 1.1432x; 1.1432x over previous
//
#include <hip/hip_runtime.h>
#include <hip/hip_fp16.h>

constexpr int FD = 256;   // feature dim (D == H == 256)

typedef _Float16 f16x8 __attribute__((ext_vector_type(8)));
typedef _Float16 f16x4 __attribute__((ext_vector_type(4)));
typedef float    f32x4 __attribute__((ext_vector_type(4)));

// ---------------- graph preprocessing ----------------

__global__ __launch_bounds__(256) void k_init(int* counts, int* fill, int n) {
    int i = blockIdx.x * 256 + threadIdx.x;
    if (i < n) { counts[i] = 0; fill[i] = 0; }
}

__global__ __launch_bounds__(256) void k_count(const int* __restrict__ dst,
                                               int* __restrict__ counts, int E) {
    int i = blockIdx.x * 256 + threadIdx.x;
    if (i < E) atomicAdd(&counts[dst[i]], 1);
}

__global__ __launch_bounds__(256) void k_dinv(const int* __restrict__ counts,
                                              float* __restrict__ dinv, int n) {
    int i = blockIdx.x * 256 + threadIdx.x;
    if (i < n) dinv[i] = rsqrtf((float)(counts[i] + 1));  // +1 = self-loop
}

__global__ __launch_bounds__(256) void k_scan(const int* __restrict__ counts,
                                              int* __restrict__ rowptr, int n) {
    __shared__ int part[256];
    int t = threadIdx.x;
    int chunk = (n + 255) >> 8;
    int b = t * chunk;
    int e = min(b + chunk, n);
    int sum = 0;
    for (int i = b; i < e; i++) sum += counts[i];
    part[t] = sum;
    __syncthreads();
    for (int o = 1; o < 256; o <<= 1) {
        int v = (t >= o) ? part[t - o] : 0;
        __syncthreads();
        part[t] += v;
        __syncthreads();
    }
    int run = (t == 0) ? 0 : part[t - 1];
    for (int i = b; i < e; i++) { rowptr[i] = run; run += counts[i]; }
    if (t == 255) rowptr[n] = run;
}

__global__ __launch_bounds__(256) void k_scatter(const int* __restrict__ src,
                                                 const int* __restrict__ dst,
                                                 const int* __restrict__ rowptr,
                                                 int* __restrict__ fill,
                                                 const float* __restrict__ dinv,
                                                 int* __restrict__ col,
                                                 float* __restrict__ val, int E) {
    int i = blockIdx.x * 256 + threadIdx.x;
    if (i < E) {
        int d = dst[i], s = src[i];
        int pos = rowptr[d] + atomicAdd(&fill[d], 1);
        col[pos] = s;
        val[pos] = dinv[s];
    }
}

// ---------------- fp32 -> fp16 casts ----------------

__global__ __launch_bounds__(256) void k_cast_x(const float* __restrict__ a,
                                                _Float16* __restrict__ o, int n8) {
    int i = blockIdx.x * 256 + threadIdx.x;
    if (i < n8) {
        float4 v0 = ((const float4*)a)[i * 2];
        float4 v1 = ((const float4*)a)[i * 2 + 1];
        f16x8 h = { (_Float16)v0.x, (_Float16)v0.y, (_Float16)v0.z, (_Float16)v0.w,
                    (_Float16)v1.x, (_Float16)v1.y, (_Float16)v1.z, (_Float16)v1.w };
        ((f16x8*)o)[i] = h;
    }
}

__global__ __launch_bounds__(256) void k_cast_w(const float* __restrict__ w1,
                                                const float* __restrict__ w2,
                                                const float* __restrict__ w3,
                                                _Float16* __restrict__ o) {
    const float* w = (blockIdx.y == 0) ? w1 : (blockIdx.y == 1) ? w2 : w3;
    _Float16* op = o + (size_t)blockIdx.y * FD * FD;
    int i = blockIdx.x * 256 + threadIdx.x;   // 8 elems per thread, 8192 threads
    float4 v0 = ((const float4*)w)[i * 2];
    float4 v1 = ((const float4*)w)[i * 2 + 1];
    f16x8 h = { (_Float16)v0.x, (_Float16)v0.y, (_Float16)v0.z, (_Float16)v0.w,
                (_Float16)v1.x, (_Float16)v1.y, (_Float16)v1.z, (_Float16)v1.w };
    ((f16x8*)op)[i] = h;
}

// ---------------- MFMA GEMM: C[m,j] = sum_k A[m,k] * W[j,k], all fp16 in, fp16 out ----
// Block: 256 threads = 4 waves, 64 rows of A staged in swizzled LDS.
// Grid.y splits the 256 output cols into 2 halves (8 col-tiles of 16 each).

__global__ __launch_bounds__(256) void k_gemm16(const _Float16* __restrict__ A,
                                                const _Float16* __restrict__ W,
                                                _Float16* __restrict__ C, int M) {
    __shared__ _Float16 As[64 * FD];   // 32 KB, XOR-swizzled 16B chunks
    int t = threadIdx.x;
    int m0 = blockIdx.x * 64;
    int c0 = blockIdx.y * 128;         // col half: 8 tiles of 16

    // stage A-strip: 64 rows x 512B = 2048 chunks of 16B, 8 per thread
    #pragma unroll
    for (int i = 0; i < 8; i++) {
        int id = i * 256 + t;
        int row = id >> 5;             // 32 chunks per row
        int c16 = id & 31;
        f16x8 v = {};
        if (m0 + row < M) v = *(const f16x8*)(A + (size_t)(m0 + row) * FD + c16 * 8);
        int byte = ((row << 9) + (c16 << 4)) ^ ((row & 7) << 4);
        *(f16x8*)((char*)As + byte) = v;
    }
    __syncthreads();

    int lane = t & 63;
    int w = t >> 6;                    // wave id 0..3 -> rows w*16..w*16+15
    int lr = lane & 15;
    int kq = lane >> 4;                // 0..3

    f32x4 acc[8] = {};
    for (int k0 = 0; k0 < FD; k0 += 32) {
        int kk = k0 + kq * 8;          // this lane's 8 K elems
        int arow = w * 16 + lr;
        int abyte = ((arow << 9) + kk * 2) ^ ((arow & 7) << 4);
        f16x8 a = *(const f16x8*)((const char*)As + abyte);
        const _Float16* wp = W + (size_t)(c0 + lr) * FD + kk;
        #pragma unroll
        for (int ct = 0; ct < 8; ct++) {
            f16x8 b = *(const f16x8*)(wp + (size_t)ct * 16 * FD);
            acc[ct] = __builtin_amdgcn_mfma_f32_16x16x32_f16(a, b, acc[ct], 0, 0, 0);
        }
    }

    // C/D layout: col = lane&15, row = (lane>>4)*4 + reg   [m89-verified]
    int orow0 = m0 + w * 16 + kq * 4;
    #pragma unroll
    for (int ct = 0; ct < 8; ct++) {
        #pragma unroll
        for (int r = 0; r < 4; r++) {
            int gr = orow0 + r;
            if (gr < M) C[(size_t)gr * FD + c0 + ct * 16 + lr] = (_Float16)acc[ct][r];
        }
    }
}

// ---------------- SpMM: out[n,:] = relu(dinv[n]*(sum val*H16[col] + dinv[n]*H16[n]) + b) ----
// One wave per row; lane owns 4 cols (8B fp16 loads). fp32 accumulate.

template<int F16OUT>
__global__ __launch_bounds__(256) void k_spmm16(const _Float16* __restrict__ H,
                                                const int* __restrict__ rowptr,
                                                const int* __restrict__ col,
                                                const float* __restrict__ val,
                                                const float* __restrict__ dinv,
                                                const float* __restrict__ bias,
                                                float* __restrict__ outf,
                                                _Float16* __restrict__ outh, int N) {
    int row = blockIdx.x * 4 + (threadIdx.x >> 6);
    if (row >= N) return;
    int lane = threadIdx.x & 63;
    int s = rowptr[row], e = rowptr[row + 1];
    float a0 = 0.f, a1 = 0.f, a2 = 0.f, a3 = 0.f;
    int i = s;
    for (; i + 1 < e; i += 2) {
        int   c0 = col[i],  c1 = col[i + 1];
        float v0 = val[i],  v1 = val[i + 1];
        f16x4 h0 = ((const f16x4*)(H + (size_t)c0 * FD))[lane];
        f16x4 h1 = ((const f16x4*)(H + (size_t)c1 * FD))[lane];
        a0 += v0 * (float)h0[0] + v1 * (float)h1[0];
        a1 += v0 * (float)h0[1] + v1 * (float)h1[1];
        a2 += v0 * (float)h0[2] + v1 * (float)h1[2];
        a3 += v0 * (float)h0[3] + v1 * (float)h1[3];
    }
    if (i < e) {
        int c = col[i];
        float v = val[i];
        f16x4 h = ((const f16x4*)(H + (size_t)c * FD))[lane];
        a0 += v * (float)h[0]; a1 += v * (float)h[1];
        a2 += v * (float)h[2]; a3 += v * (float)h[3];
    }
    float di = dinv[row];
    f16x4 hs = ((const f16x4*)(H + (size_t)row * FD))[lane];
    a0 += di * (float)hs[0]; a1 += di * (float)hs[1];
    a2 += di * (float)hs[2]; a3 += di * (float)hs[3];
    float4 bb = ((const float4*)bias)[lane];
    float o0 = fmaxf(fmaf(di, a0, bb.x), 0.f);
    float o1 = fmaxf(fmaf(di, a1, bb.y), 0.f);
    float o2 = fmaxf(fmaf(di, a2, bb.z), 0.f);
    float o3 = fmaxf(fmaf(di, a3, bb.w), 0.f);
    if (F16OUT) {
        f16x4 o = { (_Float16)o0, (_Float16)o1, (_Float16)o2, (_Float16)o3 };
        ((f16x4*)(outh + (size_t)row * FD))[lane] = o;
    } else {
        ((float4*)(outf + (size_t)row * FD))[lane] = make_float4(o0, o1, o2, o3);
    }
}

// ---------------- launch ----------------

extern "C" void kernel_launch(void* const* d_in, const int* in_sizes, int n_in,
                              void* d_out, int out_size, void* d_ws, size_t ws_size,
                              hipStream_t stream) {
    const float* x  = (const float*)d_in[0];
    const int*   ei = (const int*)d_in[1];
    const float* W1 = (const float*)d_in[2];
    const float* b1 = (const float*)d_in[3];
    const float* W2 = (const float*)d_in[4];
    const float* b2 = (const float*)d_in[5];
    const float* W3 = (const float*)d_in[6];
    const float* b3 = (const float*)d_in[7];
    float* out = (float*)d_out;

    int N = in_sizes[0] / FD;
    int E = in_sizes[1] / 2;
    const int* src = ei;
    const int* dst = ei + E;

    char* base = (char*)d_ws;
    size_t off = 0;
    auto alloc = [&](size_t bytes) {
        char* p = base + off;
        off = (off + bytes + 255) & ~(size_t)255;
        return p;
    };
    int*      counts = (int*)     alloc((size_t)N * 4);
    int*      fill   = (int*)     alloc((size_t)N * 4);
    int*      rowptr = (int*)     alloc((size_t)(N + 1) * 4);
    float*    dinv   = (float*)   alloc((size_t)N * 4);
    int*      col    = (int*)     alloc((size_t)E * 4);
    float*    val    = (float*)   alloc((size_t)E * 4);
    _Float16* x16    = (_Float16*)alloc((size_t)N * FD * 2);
    _Float16* W16    = (_Float16*)alloc((size_t)3 * FD * FD * 2);
    _Float16* Ht16   = (_Float16*)alloc((size_t)N * FD * 2);
    _Float16* buf16  = (_Float16*)alloc((size_t)N * FD * 2);

    int gN = (N + 255) / 256, gE = (E + 255) / 256;
    k_init   <<<gN, 256, 0, stream>>>(counts, fill, N);
    k_count  <<<gE, 256, 0, stream>>>(dst, counts, E);
    k_dinv   <<<gN, 256, 0, stream>>>(counts, dinv, N);
    k_scan   <<<1, 256, 0, stream>>>(counts, rowptr, N);
    k_scatter<<<gE, 256, 0, stream>>>(src, dst, rowptr, fill, dinv, col, val, E);

    k_cast_x <<<(N * FD / 8 + 255) / 256, 256, 0, stream>>>(x, x16, N * FD / 8);
    k_cast_w <<<dim3(FD * FD / 8 / 256, 3), 256, 0, stream>>>(W1, W2, W3, W16);

    dim3 gg((N + 63) / 64, 2);
    int gs = (N + 3) / 4;
    // layer 1
    k_gemm16   <<<gg, 256, 0, stream>>>(x16, W16, Ht16, N);
    k_spmm16<1><<<gs, 256, 0, stream>>>(Ht16, rowptr, col, val, dinv, b1, nullptr, buf16, N);
    // layer 2
    k_gemm16   <<<gg, 256, 0, stream>>>(buf16, W16 + (size_t)FD * FD, Ht16, N);
    k_spmm16<1><<<gs, 256, 0, stream>>>(Ht16, rowptr, col, val, dinv, b2, nullptr, buf16, N);
    // layer 3
    k_gemm16   <<<gg, 256, 0, stream>>>(buf16, W16 + (size_t)2 * FD * FD, Ht16, N);
    k_spmm16<0><<<gs, 256, 0, stream>>>(Ht16, rowptr, col, val, dinv, b3, out, nullptr, N);
}

// Round 3
// 208.859 us; speedup vs baseline: 1.2951x; 1.1329x over previous
//
#include <hip/hip_runtime.h>
#include <hip/hip_fp16.h>

constexpr int FD = 256;   // feature dim (D == H == 256)

typedef _Float16 f16x8 __attribute__((ext_vector_type(8)));
typedef _Float16 f16x4 __attribute__((ext_vector_type(4)));
typedef float    f32x4 __attribute__((ext_vector_type(4)));

// ---------------- graph preprocessing ----------------

__global__ __launch_bounds__(256) void k_init(int* counts, int* fill, int n) {
    int i = blockIdx.x * 256 + threadIdx.x;
    if (i < n) { counts[i] = 0; fill[i] = 0; }
}

__global__ __launch_bounds__(256) void k_count(const int* __restrict__ dst,
                                               int* __restrict__ counts, int E) {
    int i = blockIdx.x * 256 + threadIdx.x;
    if (i < E) atomicAdd(&counts[dst[i]], 1);
}

// exclusive scan of counts -> rowptr, plus dinv = rsqrt(deg+1)
__global__ __launch_bounds__(256) void k_scan(const int* __restrict__ counts,
                                              int* __restrict__ rowptr,
                                              float* __restrict__ dinv, int n) {
    __shared__ int part[256];
    int t = threadIdx.x;
    int chunk = (n + 255) >> 8;
    int b = t * chunk;
    int e = min(b + chunk, n);
    int sum = 0;
    for (int i = b; i < e; i++) sum += counts[i];
    part[t] = sum;
    __syncthreads();
    for (int o = 1; o < 256; o <<= 1) {
        int v = (t >= o) ? part[t - o] : 0;
        __syncthreads();
        part[t] += v;
        __syncthreads();
    }
    int run = (t == 0) ? 0 : part[t - 1];
    for (int i = b; i < e; i++) {
        rowptr[i] = run;
        run += counts[i];
        dinv[i] = rsqrtf((float)(counts[i] + 1));   // +1 = self-loop
    }
    if (t == 255) rowptr[n] = run;
}

__global__ __launch_bounds__(256) void k_scatter(const int* __restrict__ src,
                                                 const int* __restrict__ dst,
                                                 const int* __restrict__ rowptr,
                                                 int* __restrict__ fill,
                                                 const float* __restrict__ dinv,
                                                 int2* __restrict__ edges, int E) {
    int i = blockIdx.x * 256 + threadIdx.x;
    if (i < E) {
        int d = dst[i], s = src[i];
        int pos = rowptr[d] + atomicAdd(&fill[d], 1);
        edges[pos] = make_int2(s, __float_as_int(dinv[s]));
    }
}

// ---------------- fp32 -> fp16 casts ----------------

__global__ __launch_bounds__(256) void k_cast_x(const float* __restrict__ a,
                                                _Float16* __restrict__ o, int n8) {
    int i = blockIdx.x * 256 + threadIdx.x;
    if (i < n8) {
        float4 v0 = ((const float4*)a)[i * 2];
        float4 v1 = ((const float4*)a)[i * 2 + 1];
        f16x8 h = { (_Float16)v0.x, (_Float16)v0.y, (_Float16)v0.z, (_Float16)v0.w,
                    (_Float16)v1.x, (_Float16)v1.y, (_Float16)v1.z, (_Float16)v1.w };
        ((f16x8*)o)[i] = h;
    }
}

__global__ __launch_bounds__(256) void k_cast_w(const float* __restrict__ w1,
                                                const float* __restrict__ w2,
                                                const float* __restrict__ w3,
                                                _Float16* __restrict__ o) {
    const float* w = (blockIdx.y == 0) ? w1 : (blockIdx.y == 1) ? w2 : w3;
    _Float16* op = o + (size_t)blockIdx.y * FD * FD;
    int i = blockIdx.x * 256 + threadIdx.x;
    float4 v0 = ((const float4*)w)[i * 2];
    float4 v1 = ((const float4*)w)[i * 2 + 1];
    f16x8 h = { (_Float16)v0.x, (_Float16)v0.y, (_Float16)v0.z, (_Float16)v0.w,
                (_Float16)v1.x, (_Float16)v1.y, (_Float16)v1.z, (_Float16)v1.w };
    ((f16x8*)op)[i] = h;
}

// ---------------- fused GCN layer: out = relu( (Â Hin) W^T + b ) ----------------
// 16 dst rows per block, 256 threads (4 waves, 4 rows each).
// Phase 1: gather-aggregate rows into swizzled LDS tile (fp16).
// Phase 2: MFMA 16x256 tile against W (K=256), wave w owns col tiles w*4..w*4+3.
// Phase 3: bias+relu in fp32, LDS roundtrip, coalesced store.

template<int OUT32>
__global__ __launch_bounds__(256) void k_layer(const _Float16* __restrict__ Hin,
                                               const int2* __restrict__ edges,
                                               const int* __restrict__ rowptr,
                                               const float* __restrict__ dinv,
                                               const _Float16* __restrict__ W,
                                               const float* __restrict__ bias,
                                               _Float16* __restrict__ outh,
                                               float* __restrict__ outf, int N) {
    __shared__ char lds[16 * 256 * 4];      // 16 KB (A-tile fp16 8KB; C-tile up to fp32 16KB)
    int t = threadIdx.x;
    int lane = t & 63;
    int w = t >> 6;
    int m0 = blockIdx.x * 16;

    // ---- phase 1: aggregate 4 rows per wave ----
    for (int rr = 0; rr < 4; rr++) {
        int r = w * 4 + rr;                 // LDS row 0..15
        int row = m0 + r;
        f32x4 acc = {};
        if (row < N) {
            int s = rowptr[row], e = rowptr[row + 1];
            float di = dinv[row];
            int i = s;
            for (; i + 8 <= e; i += 8) {
                int2 c[8];
                #pragma unroll
                for (int u = 0; u < 8; u++) c[u] = edges[i + u];
                #pragma unroll
                for (int u = 0; u < 8; u++) {
                    f16x4 h = ((const f16x4*)(Hin + (size_t)c[u].x * FD))[lane];
                    float v = __int_as_float(c[u].y);
                    acc[0] += v * (float)h[0];
                    acc[1] += v * (float)h[1];
                    acc[2] += v * (float)h[2];
                    acc[3] += v * (float)h[3];
                }
            }
            for (; i < e; i++) {
                int2 cv = edges[i];
                f16x4 h = ((const f16x4*)(Hin + (size_t)cv.x * FD))[lane];
                float v = __int_as_float(cv.y);
                acc[0] += v * (float)h[0];
                acc[1] += v * (float)h[1];
                acc[2] += v * (float)h[2];
                acc[3] += v * (float)h[3];
            }
            // self-loop + final dinv[dst] scale
            f16x4 hs = ((const f16x4*)(Hin + (size_t)row * FD))[lane];
            acc[0] = di * (acc[0] + di * (float)hs[0]);
            acc[1] = di * (acc[1] + di * (float)hs[1]);
            acc[2] = di * (acc[2] + di * (float)hs[2]);
            acc[3] = di * (acc[3] + di * (float)hs[3]);
        }
        f16x4 o = { (_Float16)acc[0], (_Float16)acc[1], (_Float16)acc[2], (_Float16)acc[3] };
        int byte = ((r << 9) + lane * 8) ^ ((r & 7) << 4);   // XOR-swizzled 16B chunks
        *(f16x4*)(lds + byte) = o;
    }
    __syncthreads();

    // ---- phase 2: MFMA. A = LDS tile (16 rows), B = W rows (output cols) ----
    int lr = lane & 15;
    int kq = lane >> 4;                     // 0..3
    f32x4 cacc[4] = {};
    const _Float16* wp = W + (size_t)(w * 64 + lr) * FD + kq * 8;
    #pragma unroll
    for (int k0 = 0; k0 < FD; k0 += 32) {
        int abyte = ((lr << 9) + k0 * 2 + kq * 16) ^ ((lr & 7) << 4);
        f16x8 a = *(const f16x8*)(lds + abyte);
        #pragma unroll
        for (int ct = 0; ct < 4; ct++) {
            f16x8 b = *(const f16x8*)(wp + (size_t)ct * 16 * FD + k0);
            cacc[ct] = __builtin_amdgcn_mfma_f32_16x16x32_f16(a, b, cacc[ct], 0, 0, 0);
        }
    }
    __syncthreads();   // done reading A-tile; reuse LDS for C-tile

    // ---- phase 3: bias + relu (fp32), LDS roundtrip, coalesced store ----
    // C/D layout: col = lane&15, row = (lane>>4)*4 + reg  [m89-verified]
    #pragma unroll
    for (int ct = 0; ct < 4; ct++) {
        int c = w * 64 + ct * 16 + lr;
        float bb = bias[c];
        #pragma unroll
        for (int r = 0; r < 4; r++) {
            int orow = kq * 4 + r;
            float o = fmaxf(cacc[ct][r] + bb, 0.f);
            if (OUT32) ((float*)lds)[orow * FD + c] = o;
            else       ((_Float16*)lds)[orow * FD + c] = (_Float16)o;
        }
    }
    __syncthreads();
    int row = t >> 4;                       // 16 rows, 16 threads each
    int gr = m0 + row;
    if (gr < N) {
        if (OUT32) {
            const float4* src = (const float4*)((const float*)lds + row * FD) + (t & 15) * 4;
            float4* dst = (float4*)(outf + (size_t)gr * FD) + (t & 15) * 4;
            #pragma unroll
            for (int j = 0; j < 4; j++) dst[j] = src[j];
        } else {
            const f16x8* src = (const f16x8*)((const _Float16*)lds + row * FD) + (t & 15) * 2;
            f16x8* dst = (f16x8*)(outh + (size_t)gr * FD) + (t & 15) * 2;
            dst[0] = src[0];
            dst[1] = src[1];
        }
    }
}

// ---------------- launch ----------------

extern "C" void kernel_launch(void* const* d_in, const int* in_sizes, int n_in,
                              void* d_out, int out_size, void* d_ws, size_t ws_size,
                              hipStream_t stream) {
    const float* x  = (const float*)d_in[0];
    const int*   ei = (const int*)d_in[1];
    const float* W1 = (const float*)d_in[2];
    const float* b1 = (const float*)d_in[3];
    const float* W2 = (const float*)d_in[4];
    const float* b2 = (const float*)d_in[5];
    const float* W3 = (const float*)d_in[6];
    const float* b3 = (const float*)d_in[7];
    float* out = (float*)d_out;

    int N = in_sizes[0] / FD;
    int E = in_sizes[1] / 2;
    const int* src = ei;
    const int* dst = ei + E;

    char* base = (char*)d_ws;
    size_t off = 0;
    auto alloc = [&](size_t bytes) {
        char* p = base + off;
        off = (off + bytes + 255) & ~(size_t)255;
        return p;
    };
    int*      counts = (int*)     alloc((size_t)N * 4);
    int*      fill   = (int*)     alloc((size_t)N * 4);
    int*      rowptr = (int*)     alloc((size_t)(N + 1) * 4);
    float*    dinv   = (float*)   alloc((size_t)N * 4);
    int2*     edges  = (int2*)    alloc((size_t)E * 8);
    _Float16* x16    = (_Float16*)alloc((size_t)N * FD * 2);
    _Float16* W16    = (_Float16*)alloc((size_t)3 * FD * FD * 2);
    _Float16* bufA   = (_Float16*)alloc((size_t)N * FD * 2);
    _Float16* bufB   = (_Float16*)alloc((size_t)N * FD * 2);

    int gN = (N + 255) / 256, gE = (E + 255) / 256;
    k_init   <<<gN, 256, 0, stream>>>(counts, fill, N);
    k_count  <<<gE, 256, 0, stream>>>(dst, counts, E);
    k_scan   <<<1, 256, 0, stream>>>(counts, rowptr, dinv, N);
    k_scatter<<<gE, 256, 0, stream>>>(src, dst, rowptr, fill, dinv, edges, E);

    k_cast_x <<<(N * FD / 8 + 255) / 256, 256, 0, stream>>>(x, x16, N * FD / 8);
    k_cast_w <<<dim3(FD * FD / 8 / 256, 3), 256, 0, stream>>>(W1, W2, W3, W16);

    int gl = (N + 15) / 16;
    k_layer<0><<<gl, 256, 0, stream>>>(x16,  edges, rowptr, dinv, W16,
                                       b1, bufA, nullptr, N);
    k_layer<0><<<gl, 256, 0, stream>>>(bufA, edges, rowptr, dinv, W16 + (size_t)FD * FD,
                                       b2, bufB, nullptr, N);
    k_layer<1><<<gl, 256, 0, stream>>>(bufB, edges, rowptr, dinv, W16 + (size_t)2 * FD * FD,
                                       b3, nullptr, out, N);
}

// Round 4
// 192.785 us; speedup vs baseline: 1.4031x; 1.0834x over previous
//
#include <hip/hip_runtime.h>
#include <hip/hip_fp16.h>

constexpr int FD = 256;   // feature dim (D == H == 256)

typedef _Float16 f16x8 __attribute__((ext_vector_type(8)));
typedef _Float16 f16x4 __attribute__((ext_vector_type(4)));
typedef float    f32x4 __attribute__((ext_vector_type(4)));

// ---------------- prep: cast W1/W2/W3 to fp16, zero counts/fill ----------------
// grid (40, 3) x 256 threads. y selects the W matrix; y==0 blocks also zero.

__global__ __launch_bounds__(256) void k_prep(const float* __restrict__ w1,
                                              const float* __restrict__ w2,
                                              const float* __restrict__ w3,
                                              _Float16* __restrict__ o,
                                              int* __restrict__ counts,
                                              int* __restrict__ fill, int N) {
    int i = blockIdx.x * 256 + threadIdx.x;          // 0..10239
    const float* w = (blockIdx.y == 0) ? w1 : (blockIdx.y == 1) ? w2 : w3;
    _Float16* op = o + (size_t)blockIdx.y * FD * FD;
    if (i < FD * FD / 8) {
        float4 v0 = ((const float4*)w)[i * 2];
        float4 v1 = ((const float4*)w)[i * 2 + 1];
        f16x8 h = { (_Float16)v0.x, (_Float16)v0.y, (_Float16)v0.z, (_Float16)v0.w,
                    (_Float16)v1.x, (_Float16)v1.y, (_Float16)v1.z, (_Float16)v1.w };
        ((f16x8*)op)[i] = h;
    }
    if (blockIdx.y == 0 && i < N) { counts[i] = 0; fill[i] = 0; }
}

// ---------------- count degrees + cast x to fp16 (same grid: E == N*FD/8) ----

__global__ __launch_bounds__(256) void k_count_cast(const int* __restrict__ dst,
                                                    int* __restrict__ counts, int E,
                                                    const float* __restrict__ x,
                                                    _Float16* __restrict__ x16, int n8) {
    int i = blockIdx.x * 256 + threadIdx.x;
    if (i < E) atomicAdd(&counts[dst[i]], 1);
    if (i < n8) {
        float4 v0 = ((const float4*)x)[i * 2];
        float4 v1 = ((const float4*)x)[i * 2 + 1];
        f16x8 h = { (_Float16)v0.x, (_Float16)v0.y, (_Float16)v0.z, (_Float16)v0.w,
                    (_Float16)v1.x, (_Float16)v1.y, (_Float16)v1.z, (_Float16)v1.w };
        ((f16x8*)x16)[i] = h;
    }
}

// exclusive scan of counts -> rowptr, plus dinv = rsqrt(deg+1)
__global__ __launch_bounds__(256) void k_scan(const int* __restrict__ counts,
                                              int* __restrict__ rowptr,
                                              float* __restrict__ dinv, int n) {
    __shared__ int part[256];
    int t = threadIdx.x;
    int chunk = (n + 255) >> 8;
    int b = t * chunk;
    int e = min(b + chunk, n);
    int sum = 0;
    for (int i = b; i < e; i++) sum += counts[i];
    part[t] = sum;
    __syncthreads();
    for (int o = 1; o < 256; o <<= 1) {
        int v = (t >= o) ? part[t - o] : 0;
        __syncthreads();
        part[t] += v;
        __syncthreads();
    }
    int run = (t == 0) ? 0 : part[t - 1];
    for (int i = b; i < e; i++) {
        rowptr[i] = run;
        run += counts[i];
        dinv[i] = rsqrtf((float)(counts[i] + 1));   // +1 = self-loop
    }
    if (t == 255) rowptr[n] = run;
}

__global__ __launch_bounds__(256) void k_scatter(const int* __restrict__ src,
                                                 const int* __restrict__ dst,
                                                 const int* __restrict__ rowptr,
                                                 int* __restrict__ fill,
                                                 const float* __restrict__ dinv,
                                                 int2* __restrict__ edges, int E) {
    int i = blockIdx.x * 256 + threadIdx.x;
    if (i < E) {
        int d = dst[i], s = src[i];
        int pos = rowptr[d] + atomicAdd(&fill[d], 1);
        edges[pos] = make_int2(s, __float_as_int(dinv[s]));
    }
}

// ---------------- fused GCN layer: out = relu( (Â Hin) W^T + b ) ----------------
// 16 dst rows per block, 512 threads (8 waves). Wave w aggregates rows
// {2w, 2w+1} with 16-deep unrolled gather (16 outstanding 512B row reads),
// then MFMAs the 16x256 LDS tile against its 32 output cols of W.

template<int OUT32>
__global__ __launch_bounds__(512) void k_layer(const _Float16* __restrict__ Hin,
                                               const int2* __restrict__ edges,
                                               const int* __restrict__ rowptr,
                                               const float* __restrict__ dinv,
                                               const _Float16* __restrict__ W,
                                               const float* __restrict__ bias,
                                               _Float16* __restrict__ outh,
                                               float* __restrict__ outf, int N) {
    __shared__ char lds[16 * 256 * 4];      // 16 KB (A-tile fp16 8KB / C-tile fp32 16KB)
    int t = threadIdx.x;
    int lane = t & 63;
    int w = t >> 6;                          // wave 0..7
    int m0 = blockIdx.x * 16;

    // ---- phase 1: aggregate 2 rows per wave ----
    #pragma unroll
    for (int rr = 0; rr < 2; rr++) {
        int r = w * 2 + rr;                 // LDS row 0..15
        int row = m0 + r;
        float a0 = 0.f, a1 = 0.f, a2 = 0.f, a3 = 0.f;
        if (row < N) {
            int s = rowptr[row], e = rowptr[row + 1];
            float di = dinv[row];
            int i = s;
            for (; i + 16 <= e; i += 16) {
                int2 c[16];
                #pragma unroll
                for (int u = 0; u < 16; u++) c[u] = edges[i + u];
                #pragma unroll
                for (int u = 0; u < 16; u++) {
                    f16x4 h = ((const f16x4*)(Hin + (size_t)c[u].x * FD))[lane];
                    float v = __int_as_float(c[u].y);
                    a0 += v * (float)h[0];
                    a1 += v * (float)h[1];
                    a2 += v * (float)h[2];
                    a3 += v * (float)h[3];
                }
            }
            for (; i + 4 <= e; i += 4) {
                int2 c[4];
                #pragma unroll
                for (int u = 0; u < 4; u++) c[u] = edges[i + u];
                #pragma unroll
                for (int u = 0; u < 4; u++) {
                    f16x4 h = ((const f16x4*)(Hin + (size_t)c[u].x * FD))[lane];
                    float v = __int_as_float(c[u].y);
                    a0 += v * (float)h[0];
                    a1 += v * (float)h[1];
                    a2 += v * (float)h[2];
                    a3 += v * (float)h[3];
                }
            }
            for (; i < e; i++) {
                int2 cv = edges[i];
                f16x4 h = ((const f16x4*)(Hin + (size_t)cv.x * FD))[lane];
                float v = __int_as_float(cv.y);
                a0 += v * (float)h[0];
                a1 += v * (float)h[1];
                a2 += v * (float)h[2];
                a3 += v * (float)h[3];
            }
            // self-loop + final dinv[dst] scale
            f16x4 hs = ((const f16x4*)(Hin + (size_t)row * FD))[lane];
            a0 = di * (a0 + di * (float)hs[0]);
            a1 = di * (a1 + di * (float)hs[1]);
            a2 = di * (a2 + di * (float)hs[2]);
            a3 = di * (a3 + di * (float)hs[3]);
        }
        f16x4 o = { (_Float16)a0, (_Float16)a1, (_Float16)a2, (_Float16)a3 };
        int byte = ((r << 9) + lane * 8) ^ ((r & 7) << 4);   // XOR-swizzled 16B chunks
        *(f16x4*)(lds + byte) = o;
    }
    __syncthreads();

    // ---- phase 2: MFMA. A = LDS tile (16 rows), wave w owns cols w*32..w*32+31 ----
    int lr = lane & 15;
    int kq = lane >> 4;                     // 0..3
    f32x4 cacc[2] = {};
    const _Float16* wp = W + (size_t)(w * 32 + lr) * FD + kq * 8;
    #pragma unroll
    for (int k0 = 0; k0 < FD; k0 += 32) {
        int abyte = ((lr << 9) + k0 * 2 + kq * 16) ^ ((lr & 7) << 4);
        f16x8 a = *(const f16x8*)(lds + abyte);
        #pragma unroll
        for (int ct = 0; ct < 2; ct++) {
            f16x8 b = *(const f16x8*)(wp + (size_t)(ct * 16) * FD + k0);
            cacc[ct] = __builtin_amdgcn_mfma_f32_16x16x32_f16(a, b, cacc[ct], 0, 0, 0);
        }
    }
    __syncthreads();   // done reading A-tile; reuse LDS for C-tile

    // ---- phase 3: bias + relu (fp32), LDS roundtrip, coalesced store ----
    // C/D layout: col = lane&15, row = (lane>>4)*4 + reg  [m89-verified]
    #pragma unroll
    for (int ct = 0; ct < 2; ct++) {
        int c = w * 32 + ct * 16 + lr;
        float bb = bias[c];
        #pragma unroll
        for (int r2 = 0; r2 < 4; r2++) {
            int orow = kq * 4 + r2;
            float o = fmaxf(cacc[ct][r2] + bb, 0.f);
            if (OUT32) ((float*)lds)[orow * FD + c] = o;
            else       ((_Float16*)lds)[orow * FD + c] = (_Float16)o;
        }
    }
    __syncthreads();
    int row = t >> 5;                       // 16 rows, 32 threads each
    int cx = t & 31;
    int gr = m0 + row;
    if (gr < N) {
        if (OUT32) {
            const float4* srcp = (const float4*)((const float*)lds + row * FD) + cx * 2;
            float4* dstp = (float4*)(outf + (size_t)gr * FD) + cx * 2;
            dstp[0] = srcp[0];
            dstp[1] = srcp[1];
        } else {
            ((f16x8*)(outh + (size_t)gr * FD))[cx] =
                ((const f16x8*)((const _Float16*)lds + row * FD))[cx];
        }
    }
}

// ---------------- launch ----------------

extern "C" void kernel_launch(void* const* d_in, const int* in_sizes, int n_in,
                              void* d_out, int out_size, void* d_ws, size_t ws_size,
                              hipStream_t stream) {
    const float* x  = (const float*)d_in[0];
    const int*   ei = (const int*)d_in[1];
    const float* W1 = (const float*)d_in[2];
    const float* b1 = (const float*)d_in[3];
    const float* W2 = (const float*)d_in[4];
    const float* b2 = (const float*)d_in[5];
    const float* W3 = (const float*)d_in[6];
    const float* b3 = (const float*)d_in[7];
    float* out = (float*)d_out;

    int N = in_sizes[0] / FD;
    int E = in_sizes[1] / 2;
    const int* src = ei;
    const int* dst = ei + E;

    char* base = (char*)d_ws;
    size_t off = 0;
    auto alloc = [&](size_t bytes) {
        char* p = base + off;
        off = (off + bytes + 255) & ~(size_t)255;
        return p;
    };
    int*      counts = (int*)     alloc((size_t)N * 4);
    int*      fill   = (int*)     alloc((size_t)N * 4);
    int*      rowptr = (int*)     alloc((size_t)(N + 1) * 4);
    float*    dinv   = (float*)   alloc((size_t)N * 4);
    int2*     edges  = (int2*)    alloc((size_t)E * 8);
    _Float16* x16    = (_Float16*)alloc((size_t)N * FD * 2);
    _Float16* W16    = (_Float16*)alloc((size_t)3 * FD * FD * 2);
    _Float16* bufA   = (_Float16*)alloc((size_t)N * FD * 2);
    _Float16* bufB   = (_Float16*)alloc((size_t)N * FD * 2);

    int n8 = N * FD / 8;
    int gBig = (max(E, n8) + 255) / 256;
    k_prep      <<<dim3((max(FD * FD / 8, N) + 255) / 256, 3), 256, 0, stream>>>(
                  W1, W2, W3, W16, counts, fill, N);
    k_count_cast<<<gBig, 256, 0, stream>>>(dst, counts, E, x, x16, n8);
    k_scan      <<<1, 256, 0, stream>>>(counts, rowptr, dinv, N);
    k_scatter   <<<(E + 255) / 256, 256, 0, stream>>>(src, dst, rowptr, fill, dinv, edges, E);

    int gl = (N + 15) / 16;
    k_layer<0><<<gl, 512, 0, stream>>>(x16,  edges, rowptr, dinv, W16,
                                       b1, bufA, nullptr, N);
    k_layer<0><<<gl, 512, 0, stream>>>(bufA, edges, rowptr, dinv, W16 + (size_t)FD * FD,
                                       b2, bufB, nullptr, N);
    k_layer<1><<<gl, 512, 0, stream>>>(bufB, edges, rowptr, dinv, W16 + (size_t)2 * FD * FD,
                                       b3, nullptr, out, N);
}